// Round 9
// baseline (245.979 us; speedup 1.0000x reference)
//
#include <hip/hip_runtime.h>

typedef unsigned short u16;
typedef __attribute__((ext_vector_type(8))) short short8;
typedef __attribute__((ext_vector_type(4))) short short4v;
typedef __attribute__((ext_vector_type(4))) float floatx4;
typedef __attribute__((ext_vector_type(4))) unsigned short ushort4v;

#define B_ 4
#define T_ 2048
#define C_ 1024
#define H_ 16
#define HD_ 64

static __device__ __forceinline__ u16 f2bf(float f) {
  union { float f; unsigned int i; } c; c.f = f;
  unsigned int u = c.i;
  return (u16)((u + 0x7FFFu + ((u >> 16) & 1u)) >> 16);
}
// pack 2 fp32 -> bf16x2 (truncation) in one v_perm_b32
static __device__ __forceinline__ unsigned pk2(float lo, float hi) {
  union { float f; unsigned u; } a, b; a.f = hi; b.f = lo;
  return __builtin_amdgcn_perm(a.u, b.u, 0x07060302u);
}

// async global->LDS DMA, 16 B/lane; LDS dest = wave-uniform base + lane*16
static __device__ __forceinline__ void gload16(const u16* g, u16* l) {
  __builtin_amdgcn_global_load_lds(
      (const __attribute__((address_space(1))) unsigned int*)(g),
      (__attribute__((address_space(3))) unsigned int*)(l), 16, 0, 0);
}

// ---------------- fused prep: convert x + transpose both weights ----------
__global__ __launch_bounds__(256) void prep_k(const float* __restrict__ x,
                                              const float* __restrict__ w_qkv,
                                              const float* __restrict__ w_proj,
                                              u16* __restrict__ xbf,
                                              u16* __restrict__ wqkvT,
                                              u16* __restrict__ wprojT) {
  const int bid = blockIdx.x;
  if (bid < 8192) {
    const int i = bid * 256 + threadIdx.x;
    const float4 f = ((const float4*)x)[i];
    ushort4v o;
    o.x = f2bf(f.x); o.y = f2bf(f.y); o.z = f2bf(f.z); o.w = f2bf(f.w);
    *(ushort4v*)(xbf + (size_t)i * 4) = o;
    return;
  }
  __shared__ u16 tile[32][33];
  const float* in;
  u16* out;
  int R, Cc, tb;
  if (bid < 11264) {
    in = w_qkv; out = wqkvT; R = C_; Cc = 3 * C_; tb = bid - 8192;
  } else {
    in = w_proj; out = wprojT; R = C_; Cc = C_; tb = bid - 11264;
  }
  const int tpr = Cc / 32;
  const int bx = (tb % tpr) * 32;
  const int by = (tb / tpr) * 32;
  const int tx = threadIdx.x & 31;
  const int ty = threadIdx.x >> 5;
  #pragma unroll
  for (int i = ty; i < 32; i += 8)
    tile[i][tx] = f2bf(in[(size_t)(by + i) * Cc + bx + tx]);
  __syncthreads();
  #pragma unroll
  for (int i = ty; i < 32; i += 8)
    out[(size_t)(bx + i) * R + by + tx] = tile[tx][i];
}

// ---------------- V transpose: qkv natural -> Vt[bh][hd][t] ----------------
__global__ __launch_bounds__(256) void vtrans_k(const u16* __restrict__ qkv,
                                                u16* __restrict__ vt) {
  __shared__ u16 tile[64][74];
  const int tt = blockIdx.x;
  const int bh = blockIdx.y;
  const int b = bh >> 4, h = bh & 15;
  const int tid = threadIdx.x;
  const u16* src = qkv + ((size_t)b * T_ + tt * 64) * (3 * C_) + 2 * C_ + h * HD_;
  #pragma unroll
  for (int ss = tid; ss < 512; ss += 256) {
    const int row = ss >> 3, c8 = (ss & 7) * 8;
    *(short8*)(&tile[row][c8]) = *(const short8*)(src + (size_t)row * (3 * C_) + c8);
  }
  __syncthreads();
  u16* dst = vt + (size_t)bh * HD_ * T_ + tt * 64;
  #pragma unroll
  for (int ss = tid; ss < 512; ss += 256) {
    const int tc = (ss & 7) * 8, d = ss >> 3;
    short8 o;
    #pragma unroll
    for (int j = 0; j < 8; j++) o[j] = (short)tile[tc + j][d];
    *(short8*)(dst + (size_t)d * T_ + tc) = o;
  }
}

// ---------------- GEMM, B^T operand, BK=64, XCD-swizzled 1D grid ----------
// tM = (bid&7)*8 + (s&7): each XCD keeps its 8 A-row-panels L2-resident.
// MODE 1: bf16 out. MODE 2: fp32 out + bias, nontemporal (never re-read).
template <int MODE>
__global__ __launch_bounds__(256) void gemm_bt(const u16* __restrict__ A,
                                               const u16* __restrict__ Bt,
                                               u16* __restrict__ outb,
                                               float* __restrict__ outf,
                                               const float* __restrict__ bias,
                                               int M, int N, int K) {
  __shared__ __align__(16) u16 As[2][128 * 32];
  __shared__ __align__(16) u16 Bs[2][128 * 32];
  const int bid = blockIdx.x;
  const int s = bid >> 3;
  const int tM = ((bid & 7) * 8 + (s & 7)) * 128;  // 64 M-tiles = 8 XCD x 8
  const int tN = (s >> 3) * 128;
  const int tid = threadIdx.x;
  const int wave = tid >> 6;
  const int lane = tid & 63;
  const int lr = lane & 15;
  const int quad = lane >> 4;
  const int wm = (wave >> 1) * 64;
  const int wn = (wave & 1) * 64;

  const int srow = lane >> 2;
  const int skofs = ((lane & 3) ^ ((lane >> 3) & 3)) * 8;

  const floatx4 zf = {0.f, 0.f, 0.f, 0.f};
  floatx4 acc[4][4];
  #pragma unroll
  for (int i = 0; i < 4; i++)
    #pragma unroll
    for (int j = 0; j < 4; j++) acc[i][j] = zf;

  const int csw = (lr >> 1) & 3;

  for (int k0 = 0; k0 < K; k0 += 64) {
    __syncthreads();
    #pragma unroll
    for (int half = 0; half < 2; half++) {
      const int kk = k0 + half * 32;
      #pragma unroll
      for (int j = 0; j < 2; j++) {
        const int seg = wave * 2 + j;
        const int row = seg * 16 + srow;
        gload16(A + (size_t)(tM + row) * K + kk + skofs, &As[half][seg * 512]);
        gload16(Bt + (size_t)(tN + row) * K + kk + skofs, &Bs[half][seg * 512]);
      }
    }
    __syncthreads();

    #pragma unroll
    for (int half = 0; half < 2; half++) {
      short8 af[4], bfr[4];
      #pragma unroll
      for (int mt = 0; mt < 4; mt++)
        af[mt] = *(const short8*)(&As[half][(wm + mt * 16 + lr) * 32 + ((quad ^ csw) * 8)]);
      #pragma unroll
      for (int nt = 0; nt < 4; nt++)
        bfr[nt] = *(const short8*)(&Bs[half][(wn + nt * 16 + lr) * 32 + ((quad ^ csw) * 8)]);
      #pragma unroll
      for (int mt = 0; mt < 4; mt++)
        #pragma unroll
        for (int nt = 0; nt < 4; nt++)
          acc[mt][nt] = __builtin_amdgcn_mfma_f32_16x16x32_bf16(af[mt], bfr[nt],
                                                                acc[mt][nt], 0, 0, 0);
    }
  }

  #pragma unroll
  for (int mt = 0; mt < 4; mt++) {
    const int m0 = tM + wm + mt * 16 + quad * 4;
    #pragma unroll
    for (int nt = 0; nt < 4; nt++) {
      const int n = tN + wn + nt * 16 + lr;
      #pragma unroll
      for (int r = 0; r < 4; r++) {
        const float v = acc[mt][nt][r];
        const size_t m = (size_t)(m0 + r);
        if (MODE == 2) __builtin_nontemporal_store(v + bias[n], &outf[m * N + n]);
        else           outb[m * N + n] = f2bf(v);
      }
    }
  }
}

// ---------------- causal flash attention: S^T/O^T form, register-P --------
// grid 1024 (XCD-swizzled). Row-sum via ones-MFMA (l = 1*P^T), perm-packed P.
__global__ __launch_bounds__(256, 4) void attn_k(const u16* __restrict__ qkv,
                                                 const u16* __restrict__ vt,
                                                 u16* __restrict__ y) {
  __shared__ __align__(16) u16 Ks[64 * 64];     // [kpos][d], chunk-swizzled
  __shared__ __align__(16) u16 Vs[64 * 64];     // Vt: [d][kpos], chunk-swizzled
  const int bid = blockIdx.x;
  const int s = bid >> 3;
  const int qp = s >> 3;                     // 0..15
  const int bh = ((s & 7) << 3) | (bid & 7); // all qp of this bh share XCD
  const int b = bh >> 4, h = bh & 15;
  const int tid = threadIdx.x;
  const int wave = tid >> 6;
  const int lane = tid & 63;
  const int lr = lane & 15;
  const int quad = lane >> 4;
  const int qtA = qp, qtB = 31 - qp;

  const int srow = lane >> 3;
  const int skofs = ((lane & 7) ^ ((lane >> 3) & 7)) * 8;
  const int gsw = lr & 7;

  const size_t RS = 3 * C_;
  const u16* qcol = qkv + (size_t)b * T_ * RS + h * HD_;
  const u16* kcol = qcol + C_;

  const size_t qrA = (size_t)(qtA * 64 + wave * 16 + lr) * RS;
  const size_t qrB = (size_t)(qtB * 64 + wave * 16 + lr) * RS;
  const short8 aq0A = *(const short8*)(qcol + qrA + quad * 8);
  const short8 aq1A = *(const short8*)(qcol + qrA + 32 + quad * 8);
  const short8 aq0B = *(const short8*)(qcol + qrB + quad * 8);
  const short8 aq1B = *(const short8*)(qcol + qrB + 32 + quad * 8);

  const floatx4 zf = {0.f, 0.f, 0.f, 0.f};
  const float C1 = 0.125f * 1.44269504f;
  const float C2 = -16.0f * 1.44269504f;
  const short8 vones = {16256, 16256, 16256, 16256, 16256, 16256, 16256, 16256};

  floatx4 accA[4], accB[4];  // O^T: lane holds O^T[d=dt*16+quad*4+r][q=lr]
  floatx4 accSA = zf, accSB = zf;  // row sums via ones-MFMA
  #pragma unroll
  for (int i = 0; i < 4; i++) { accA[i] = zf; accB[i] = zf; }

  for (int kt = 0; kt <= qtB; kt++) {
    const bool doA = (kt <= qtA);
    const bool diagA = (kt == qtA), diagB = (kt == qtB);
    __syncthreads();
    #pragma unroll
    for (int j = 0; j < 2; j++) {
      const int seg = wave * 2 + j;
      const int row = seg * 8 + srow;
      gload16(kcol + (size_t)(kt * 64 + row) * RS + skofs, &Ks[seg * 512]);
      gload16(vt + ((size_t)bh * HD_ + row) * T_ + kt * 64 + skofs, &Vs[seg * 512]);
    }
    __syncthreads();

    // S^T per kpos-tile nt: lane gets P^T[kpos=nt*16+quad*4+r][q=lr]
    float peA[4][4], peB[4][4];
    #pragma unroll
    for (int nt = 0; nt < 4; nt++) {
      const short8 bk0 =
          *(const short8*)(&Ks[(nt * 16 + lr) * 64 + ((quad ^ gsw) * 8)]);
      const short8 bk1 =
          *(const short8*)(&Ks[(nt * 16 + lr) * 64 + (((quad + 4) ^ gsw) * 8)]);
      {
        floatx4 st = __builtin_amdgcn_mfma_f32_16x16x32_bf16(
            bk1, aq1B,
            __builtin_amdgcn_mfma_f32_16x16x32_bf16(bk0, aq0B, zf, 0, 0, 0),
            0, 0, 0);
        #pragma unroll
        for (int r = 0; r < 4; r++) {
          float pe = __builtin_amdgcn_exp2f(fmaf(st[r], C1, C2));
          if (diagB && (nt * 16 + quad * 4 + r > wave * 16 + lr)) pe = 0.f;
          peB[nt][r] = pe;
        }
      }
      if (doA) {
        floatx4 st = __builtin_amdgcn_mfma_f32_16x16x32_bf16(
            bk1, aq1A,
            __builtin_amdgcn_mfma_f32_16x16x32_bf16(bk0, aq0A, zf, 0, 0, 0),
            0, 0, 0);
        #pragma unroll
        for (int r = 0; r < 4; r++) {
          float pe = __builtin_amdgcn_exp2f(fmaf(st[r], C1, C2));
          if (diagA && (nt * 16 + quad * 4 + r > wave * 16 + lr)) pe = 0.f;
          peA[nt][r] = pe;
        }
      }
    }

    // pack P^T B-frags in-register via v_perm (kpos perm κ)
    short8 pB[2], pA[2];
    #pragma unroll
    for (int h2 = 0; h2 < 2; h2++) {
      union { unsigned u[4]; short8 s8; } w;
      w.u[0] = pk2(peB[2 * h2][0], peB[2 * h2][1]);
      w.u[1] = pk2(peB[2 * h2][2], peB[2 * h2][3]);
      w.u[2] = pk2(peB[2 * h2 + 1][0], peB[2 * h2 + 1][1]);
      w.u[3] = pk2(peB[2 * h2 + 1][2], peB[2 * h2 + 1][3]);
      pB[h2] = w.s8;
    }
    if (doA) {
      #pragma unroll
      for (int h2 = 0; h2 < 2; h2++) {
        union { unsigned u[4]; short8 s8; } w;
        w.u[0] = pk2(peA[2 * h2][0], peA[2 * h2][1]);
        w.u[1] = pk2(peA[2 * h2][2], peA[2 * h2][3]);
        w.u[2] = pk2(peA[2 * h2 + 1][0], peA[2 * h2 + 1][1]);
        w.u[3] = pk2(peA[2 * h2 + 1][2], peA[2 * h2 + 1][3]);
        pA[h2] = w.s8;
      }
    }

    // O^T += V^T·P^T ; row-sum += 1·P^T (ones-MFMA)
    #pragma unroll
    for (int h2 = 0; h2 < 2; h2++) {
      accSB = __builtin_amdgcn_mfma_f32_16x16x32_bf16(vones, pB[h2], accSB, 0, 0, 0);
      if (doA)
        accSA = __builtin_amdgcn_mfma_f32_16x16x32_bf16(vones, pA[h2], accSA, 0, 0, 0);
      #pragma unroll
      for (int dt = 0; dt < 4; dt++) {
        const int base = (dt * 16 + lr) * 64;
        const int cl = h2 * 4 + (quad >> 1);
        const int off_lo = ((cl ^ gsw) * 8) + (quad & 1) * 4;
        const int off_hi = (((cl + 2) ^ gsw) * 8) + (quad & 1) * 4;
        const short4v vlo = *(const short4v*)(&Vs[base + off_lo]);
        const short4v vhi = *(const short4v*)(&Vs[base + off_hi]);
        const short8 av = __builtin_shufflevector(vlo, vhi, 0, 1, 2, 3, 4, 5, 6, 7);
        accB[dt] = __builtin_amdgcn_mfma_f32_16x16x32_bf16(av, pB[h2], accB[dt], 0, 0, 0);
        if (doA)
          accA[dt] = __builtin_amdgcn_mfma_f32_16x16x32_bf16(av, pA[h2], accA[dt], 0, 0, 0);
      }
    }
  }

  // epilogue: every lane already holds the full row-sum in accS*[0]
  #pragma unroll
  for (int ph = 0; ph < 2; ph++) {
    const int qt = ph ? qtB : qtA;
    const floatx4* acc = ph ? accB : accA;
    const float inv = 1.f / (ph ? accSB[0] : accSA[0]);
    const int qg = qt * 64 + wave * 16 + lr;
    u16* yrow = y + ((size_t)(b * T_ + qg)) * C_ + h * HD_;
    #pragma unroll
    for (int dt = 0; dt < 4; dt++) {
      ushort4v o;
      #pragma unroll
      for (int r = 0; r < 4; r++) o[r] = f2bf(acc[dt][r] * inv);
      *(ushort4v*)(yrow + dt * 16 + quad * 4) = o;
    }
  }
}

extern "C" void kernel_launch(void* const* d_in, const int* in_sizes, int n_in,
                              void* d_out, int out_size, void* d_ws, size_t ws_size,
                              hipStream_t stream) {
  const float* x      = (const float*)d_in[0];  // [B,T,C] fp32
  const float* w_qkv  = (const float*)d_in[1];  // [C,3C]  fp32
  const float* w_proj = (const float*)d_in[2];  // [C,C]   fp32
  const float* b_proj = (const float*)d_in[3];  // [C]     fp32
  float* out = (float*)d_out;                   // [B,T,C] fp32

  u16* ws = (u16*)d_ws;
  const size_t SZ = (size_t)B_ * T_ * C_;          // 8388608
  u16* xbf    = ws;                                // [B,T,C] bf16 (yw aliases later)
  u16* wqkvT  = xbf + SZ;                          // [3C][C]
  u16* wprojT = wqkvT + (size_t)3 * C_ * C_;       // [C][C]
  u16* qkvw   = wprojT + (size_t)C_ * C_;          // [B,T,3C] natural bf16
  u16* vtw    = qkvw + 3 * SZ;                     // [B,H,HD,T]
  u16* yw     = xbf;                               // x dead after gemm1

  prep_k<<<12288, 256, 0, stream>>>(x, w_qkv, w_proj, xbf, wqkvT, wprojT);
  gemm_bt<1><<<1536, 256, 0, stream>>>(
      xbf, wqkvT, qkvw, nullptr, nullptr, B_ * T_, 3 * C_, C_);
  vtrans_k<<<dim3(T_ / 64, B_ * H_), 256, 0, stream>>>(qkvw, vtw);
  attn_k<<<1024, 256, 0, stream>>>(qkvw, vtw, yw);
  gemm_bt<2><<<512, 256, 0, stream>>>(
      yw, wprojT, nullptr, out, b_proj, B_ * T_, C_, C_);
}

// Round 11
// 240.225 us; speedup vs baseline: 1.0240x; 1.0240x over previous
//
#include <hip/hip_runtime.h>

typedef unsigned short u16;
typedef __attribute__((ext_vector_type(8))) short short8;
typedef __attribute__((ext_vector_type(4))) short short4v;
typedef __attribute__((ext_vector_type(4))) float floatx4;
typedef __attribute__((ext_vector_type(4))) unsigned short ushort4v;

#define B_ 4
#define T_ 2048
#define C_ 1024
#define H_ 16
#define HD_ 64

static __device__ __forceinline__ u16 f2bf(float f) {
  union { float f; unsigned int i; } c; c.f = f;
  unsigned int u = c.i;
  return (u16)((u + 0x7FFFu + ((u >> 16) & 1u)) >> 16);
}
// pack 2 fp32 -> bf16x2 (truncation) in one v_perm_b32
static __device__ __forceinline__ unsigned pk2(float lo, float hi) {
  union { float f; unsigned u; } a, b; a.f = hi; b.f = lo;
  return __builtin_amdgcn_perm(a.u, b.u, 0x07060302u);
}
// pack 2 fp32 -> bf16x2 with round-to-nearest
static __device__ __forceinline__ unsigned pk2r(float lo, float hi) {
  return (unsigned)f2bf(lo) | ((unsigned)f2bf(hi) << 16);
}

// async global->LDS DMA, 16 B/lane; LDS dest = wave-uniform base + lane*16
static __device__ __forceinline__ void gload16(const u16* g, u16* l) {
  __builtin_amdgcn_global_load_lds(
      (const __attribute__((address_space(1))) unsigned int*)(g),
      (__attribute__((address_space(3))) unsigned int*)(l), 16, 0, 0);
}

// ---------------- fused prep: convert x + transpose both weights ----------
__global__ __launch_bounds__(256) void prep_k(const float* __restrict__ x,
                                              const float* __restrict__ w_qkv,
                                              const float* __restrict__ w_proj,
                                              u16* __restrict__ xbf,
                                              u16* __restrict__ wqkvT,
                                              u16* __restrict__ wprojT) {
  const int bid = blockIdx.x;
  if (bid < 8192) {
    const int i = bid * 256 + threadIdx.x;
    const float4 f = ((const float4*)x)[i];
    ushort4v o;
    o.x = f2bf(f.x); o.y = f2bf(f.y); o.z = f2bf(f.z); o.w = f2bf(f.w);
    *(ushort4v*)(xbf + (size_t)i * 4) = o;
    return;
  }
  __shared__ u16 tile[32][33];
  const float* in;
  u16* out;
  int R, Cc, tb;
  if (bid < 11264) {
    in = w_qkv; out = wqkvT; R = C_; Cc = 3 * C_; tb = bid - 8192;
  } else {
    in = w_proj; out = wprojT; R = C_; Cc = C_; tb = bid - 11264;
  }
  const int tpr = Cc / 32;
  const int bx = (tb % tpr) * 32;
  const int by = (tb / tpr) * 32;
  const int tx = threadIdx.x & 31;
  const int ty = threadIdx.x >> 5;
  #pragma unroll
  for (int i = ty; i < 32; i += 8)
    tile[i][tx] = f2bf(in[(size_t)(by + i) * Cc + bx + tx]);
  __syncthreads();
  #pragma unroll
  for (int i = ty; i < 32; i += 8)
    out[(size_t)(bx + i) * R + by + tx] = tile[tx][i];
}

// ---------------- GEMM, B^T operand, BK=64, XCD-swizzled 1D grid ----------
// MODE 1: qkv GEMM. Q/K tiles (tN < 2C) -> natural bf16 rows of qkv buffer.
//         V tiles (tN >= 2C) -> Vt[bh][hd][t] via in-LDS 2-pass transpose.
// MODE 2: fp32 out + bias, nontemporal.
template <int MODE>
__global__ __launch_bounds__(256) void gemm_bt(const u16* __restrict__ A,
                                               const u16* __restrict__ Bt,
                                               u16* __restrict__ outb,
                                               u16* __restrict__ outv,
                                               float* __restrict__ outf,
                                               const float* __restrict__ bias,
                                               int M, int N, int K) {
  __shared__ __align__(16) u16 lds[16384];  // staging: As[2][4096] | Bs[2][4096]
  const int bid = blockIdx.x;
  const int s = bid >> 3;
  const int tM = ((bid & 7) * 8 + (s & 7)) * 128;  // 64 M-tiles = 8 XCD x 8
  const int tN = (s >> 3) * 128;
  const int tid = threadIdx.x;
  const int wave = tid >> 6;
  const int lane = tid & 63;
  const int lr = lane & 15;
  const int quad = lane >> 4;
  const int wm = (wave >> 1) * 64;
  const int wn = (wave & 1) * 64;

  const int srow = lane >> 2;
  const int skofs = ((lane & 3) ^ ((lane >> 3) & 3)) * 8;

  const floatx4 zf = {0.f, 0.f, 0.f, 0.f};
  floatx4 acc[4][4];
  #pragma unroll
  for (int i = 0; i < 4; i++)
    #pragma unroll
    for (int j = 0; j < 4; j++) acc[i][j] = zf;

  const int csw = (lr >> 1) & 3;

  for (int k0 = 0; k0 < K; k0 += 64) {
    __syncthreads();
    #pragma unroll
    for (int half = 0; half < 2; half++) {
      const int kk = k0 + half * 32;
      #pragma unroll
      for (int j = 0; j < 2; j++) {
        const int seg = wave * 2 + j;
        const int row = seg * 16 + srow;
        gload16(A + (size_t)(tM + row) * K + kk + skofs, &lds[half * 4096 + seg * 512]);
        gload16(Bt + (size_t)(tN + row) * K + kk + skofs, &lds[8192 + half * 4096 + seg * 512]);
      }
    }
    __syncthreads();

    #pragma unroll
    for (int half = 0; half < 2; half++) {
      short8 af[4], bfr[4];
      #pragma unroll
      for (int mt = 0; mt < 4; mt++)
        af[mt] = *(const short8*)(&lds[half * 4096 + (wm + mt * 16 + lr) * 32 + ((quad ^ csw) * 8)]);
      #pragma unroll
      for (int nt = 0; nt < 4; nt++)
        bfr[nt] = *(const short8*)(&lds[8192 + half * 4096 + (wn + nt * 16 + lr) * 32 + ((quad ^ csw) * 8)]);
      #pragma unroll
      for (int mt = 0; mt < 4; mt++)
        #pragma unroll
        for (int nt = 0; nt < 4; nt++)
          acc[mt][nt] = __builtin_amdgcn_mfma_f32_16x16x32_bf16(af[mt], bfr[nt],
                                                                acc[mt][nt], 0, 0, 0);
    }
  }

  if (MODE == 1 && tN >= 2 * C_) {
    // V tile: transpose 128x128 through LDS (2 passes of 64 n-rows), write Vt.
    // LDS stride 136 u16 -> write banks 2-way (free). Rows: hd; cols: t.
    const int b = tM >> 11;
    const int t0 = tM & (T_ - 1);               // within-batch t offset (FIX)
    const int h0 = (tN - 2 * C_) >> 6;          // head of nrel<64; h0+1 for >=64
    #pragma unroll
    for (int pass = 0; pass < 2; pass++) {
      __syncthreads();
      if ((wave & 1) == pass) {                 // waves with wn == pass*64 own it
        #pragma unroll
        for (int nt = 0; nt < 4; nt++) {
          const int nr = nt * 16 + lr;          // 0..63 within pass
          #pragma unroll
          for (int mt = 0; mt < 4; mt++) {
            const int mr = wm + mt * 16 + quad * 4;
            *(unsigned*)(&lds[nr * 136 + mr]) = pk2r(acc[mt][nt][0], acc[mt][nt][1]);
            *(unsigned*)(&lds[nr * 136 + mr + 2]) = pk2r(acc[mt][nt][2], acc[mt][nt][3]);
          }
        }
      }
      __syncthreads();
      const int bh = b * H_ + h0 + pass;
      u16* vbase = outv + (size_t)bh * HD_ * T_ + t0;
      #pragma unroll
      for (int i = 0; i < 4; i++) {
        const int c = tid + i * 256;            // 1024 chunks of 8 u16
        const int nr = c >> 4, m8 = (c & 15) * 8;
        const short8 v = *(const short8*)(&lds[nr * 136 + m8]);
        *(short8*)(vbase + (size_t)nr * T_ + m8) = v;
      }
    }
    return;
  }

  // natural epilogue: D[row=quad*4+r][col=lane&15]
  #pragma unroll
  for (int mt = 0; mt < 4; mt++) {
    const int m0 = tM + wm + mt * 16 + quad * 4;
    #pragma unroll
    for (int nt = 0; nt < 4; nt++) {
      const int n = tN + wn + nt * 16 + lr;
      #pragma unroll
      for (int r = 0; r < 4; r++) {
        const float v = acc[mt][nt][r];
        const size_t m = (size_t)(m0 + r);
        if (MODE == 2) __builtin_nontemporal_store(v + bias[n], &outf[m * N + n]);
        else           outb[m * N + n] = f2bf(v);
      }
    }
  }
}

// ---------------- causal flash attention: S^T/O^T form, register-P --------
// grid 1024 (XCD-swizzled). Row-sum via ones-MFMA (l = 1*P^T), perm-packed P.
__global__ __launch_bounds__(256, 4) void attn_k(const u16* __restrict__ qkv,
                                                 const u16* __restrict__ vt,
                                                 u16* __restrict__ y) {
  __shared__ __align__(16) u16 Ks[64 * 64];     // [kpos][d], chunk-swizzled
  __shared__ __align__(16) u16 Vs[64 * 64];     // Vt: [d][kpos], chunk-swizzled
  const int bid = blockIdx.x;
  const int s = bid >> 3;
  const int qp = s >> 3;                     // 0..15
  const int bh = ((s & 7) << 3) | (bid & 7); // all qp of this bh share XCD
  const int b = bh >> 4, h = bh & 15;
  const int tid = threadIdx.x;
  const int wave = tid >> 6;
  const int lane = tid & 63;
  const int lr = lane & 15;
  const int quad = lane >> 4;
  const int qtA = qp, qtB = 31 - qp;

  const int srow = lane >> 3;
  const int skofs = ((lane & 7) ^ ((lane >> 3) & 7)) * 8;
  const int gsw = lr & 7;

  const size_t RS = 3 * C_;
  const u16* qcol = qkv + (size_t)b * T_ * RS + h * HD_;
  const u16* kcol = qcol + C_;

  const size_t qrA = (size_t)(qtA * 64 + wave * 16 + lr) * RS;
  const size_t qrB = (size_t)(qtB * 64 + wave * 16 + lr) * RS;
  const short8 aq0A = *(const short8*)(qcol + qrA + quad * 8);
  const short8 aq1A = *(const short8*)(qcol + qrA + 32 + quad * 8);
  const short8 aq0B = *(const short8*)(qcol + qrB + quad * 8);
  const short8 aq1B = *(const short8*)(qcol + qrB + 32 + quad * 8);

  const floatx4 zf = {0.f, 0.f, 0.f, 0.f};
  const float C1 = 0.125f * 1.44269504f;
  const float C2 = -16.0f * 1.44269504f;
  const short8 vones = {16256, 16256, 16256, 16256, 16256, 16256, 16256, 16256};

  floatx4 accA[4], accB[4];  // O^T: lane holds O^T[d=dt*16+quad*4+r][q=lr]
  floatx4 accSA = zf, accSB = zf;  // row sums via ones-MFMA
  #pragma unroll
  for (int i = 0; i < 4; i++) { accA[i] = zf; accB[i] = zf; }

  for (int kt = 0; kt <= qtB; kt++) {
    const bool doA = (kt <= qtA);
    const bool diagA = (kt == qtA), diagB = (kt == qtB);
    __syncthreads();
    #pragma unroll
    for (int j = 0; j < 2; j++) {
      const int seg = wave * 2 + j;
      const int row = seg * 8 + srow;
      gload16(kcol + (size_t)(kt * 64 + row) * RS + skofs, &Ks[seg * 512]);
      gload16(vt + ((size_t)bh * HD_ + row) * T_ + kt * 64 + skofs, &Vs[seg * 512]);
    }
    __syncthreads();

    // S^T per kpos-tile nt: lane gets P^T[kpos=nt*16+quad*4+r][q=lr]
    float peA[4][4], peB[4][4];
    #pragma unroll
    for (int nt = 0; nt < 4; nt++) {
      const short8 bk0 =
          *(const short8*)(&Ks[(nt * 16 + lr) * 64 + ((quad ^ gsw) * 8)]);
      const short8 bk1 =
          *(const short8*)(&Ks[(nt * 16 + lr) * 64 + (((quad + 4) ^ gsw) * 8)]);
      {
        floatx4 st = __builtin_amdgcn_mfma_f32_16x16x32_bf16(
            bk1, aq1B,
            __builtin_amdgcn_mfma_f32_16x16x32_bf16(bk0, aq0B, zf, 0, 0, 0),
            0, 0, 0);
        #pragma unroll
        for (int r = 0; r < 4; r++) {
          float pe = __builtin_amdgcn_exp2f(fmaf(st[r], C1, C2));
          if (diagB && (nt * 16 + quad * 4 + r > wave * 16 + lr)) pe = 0.f;
          peB[nt][r] = pe;
        }
      }
      if (doA) {
        floatx4 st = __builtin_amdgcn_mfma_f32_16x16x32_bf16(
            bk1, aq1A,
            __builtin_amdgcn_mfma_f32_16x16x32_bf16(bk0, aq0A, zf, 0, 0, 0),
            0, 0, 0);
        #pragma unroll
        for (int r = 0; r < 4; r++) {
          float pe = __builtin_amdgcn_exp2f(fmaf(st[r], C1, C2));
          if (diagA && (nt * 16 + quad * 4 + r > wave * 16 + lr)) pe = 0.f;
          peA[nt][r] = pe;
        }
      }
    }

    // pack P^T B-frags in-register via v_perm (kpos perm κ)
    short8 pB[2], pA[2];
    #pragma unroll
    for (int h2 = 0; h2 < 2; h2++) {
      union { unsigned u[4]; short8 s8; } w;
      w.u[0] = pk2(peB[2 * h2][0], peB[2 * h2][1]);
      w.u[1] = pk2(peB[2 * h2][2], peB[2 * h2][3]);
      w.u[2] = pk2(peB[2 * h2 + 1][0], peB[2 * h2 + 1][1]);
      w.u[3] = pk2(peB[2 * h2 + 1][2], peB[2 * h2 + 1][3]);
      pB[h2] = w.s8;
    }
    if (doA) {
      #pragma unroll
      for (int h2 = 0; h2 < 2; h2++) {
        union { unsigned u[4]; short8 s8; } w;
        w.u[0] = pk2(peA[2 * h2][0], peA[2 * h2][1]);
        w.u[1] = pk2(peA[2 * h2][2], peA[2 * h2][3]);
        w.u[2] = pk2(peA[2 * h2 + 1][0], peA[2 * h2 + 1][1]);
        w.u[3] = pk2(peA[2 * h2 + 1][2], peA[2 * h2 + 1][3]);
        pA[h2] = w.s8;
      }
    }

    // O^T += V^T·P^T ; row-sum += 1·P^T (ones-MFMA)
    #pragma unroll
    for (int h2 = 0; h2 < 2; h2++) {
      accSB = __builtin_amdgcn_mfma_f32_16x16x32_bf16(vones, pB[h2], accSB, 0, 0, 0);
      if (doA)
        accSA = __builtin_amdgcn_mfma_f32_16x16x32_bf16(vones, pA[h2], accSA, 0, 0, 0);
      #pragma unroll
      for (int dt = 0; dt < 4; dt++) {
        const int base = (dt * 16 + lr) * 64;
        const int cl = h2 * 4 + (quad >> 1);
        const int off_lo = ((cl ^ gsw) * 8) + (quad & 1) * 4;
        const int off_hi = (((cl + 2) ^ gsw) * 8) + (quad & 1) * 4;
        const short4v vlo = *(const short4v*)(&Vs[base + off_lo]);
        const short4v vhi = *(const short4v*)(&Vs[base + off_hi]);
        const short8 av = __builtin_shufflevector(vlo, vhi, 0, 1, 2, 3, 4, 5, 6, 7);
        accB[dt] = __builtin_amdgcn_mfma_f32_16x16x32_bf16(av, pB[h2], accB[dt], 0, 0, 0);
        if (doA)
          accA[dt] = __builtin_amdgcn_mfma_f32_16x16x32_bf16(av, pA[h2], accA[dt], 0, 0, 0);
      }
    }
  }

  // epilogue: every lane already holds the full row-sum in accS*[0]
  #pragma unroll
  for (int ph = 0; ph < 2; ph++) {
    const int qt = ph ? qtB : qtA;
    const floatx4* acc = ph ? accB : accA;
    const float inv = 1.f / (ph ? accSB[0] : accSA[0]);
    const int qg = qt * 64 + wave * 16 + lr;
    u16* yrow = y + ((size_t)(b * T_ + qg)) * C_ + h * HD_;
    #pragma unroll
    for (int dt = 0; dt < 4; dt++) {
      ushort4v o;
      #pragma unroll
      for (int r = 0; r < 4; r++) o[r] = f2bf(acc[dt][r] * inv);
      *(ushort4v*)(yrow + dt * 16 + quad * 4) = o;
    }
  }
}

extern "C" void kernel_launch(void* const* d_in, const int* in_sizes, int n_in,
                              void* d_out, int out_size, void* d_ws, size_t ws_size,
                              hipStream_t stream) {
  const float* x      = (const float*)d_in[0];  // [B,T,C] fp32
  const float* w_qkv  = (const float*)d_in[1];  // [C,3C]  fp32
  const float* w_proj = (const float*)d_in[2];  // [C,C]   fp32
  const float* b_proj = (const float*)d_in[3];  // [C]     fp32
  float* out = (float*)d_out;                   // [B,T,C] fp32

  u16* ws = (u16*)d_ws;
  const size_t SZ = (size_t)B_ * T_ * C_;          // 8388608
  u16* xbf    = ws;                                // [B,T,C] bf16 (yw aliases later)
  u16* wqkvT  = xbf + SZ;                          // [3C][C]
  u16* wprojT = wqkvT + (size_t)3 * C_ * C_;       // [C][C]
  u16* qkvw   = wprojT + (size_t)C_ * C_;          // [B,T,3C] natural bf16 (V third unused)
  u16* vtw    = qkvw + 3 * SZ;                     // [B,H,HD,T]
  u16* yw     = xbf;                               // x dead after gemm1

  prep_k<<<12288, 256, 0, stream>>>(x, w_qkv, w_proj, xbf, wqkvT, wprojT);
  gemm_bt<1><<<1536, 256, 0, stream>>>(
      xbf, wqkvT, qkvw, vtw, nullptr, nullptr, B_ * T_, 3 * C_, C_);
  attn_k<<<1024, 256, 0, stream>>>(qkvw, vtw, yw);
  gemm_bt<2><<<512, 256, 0, stream>>>(
      yw, wprojT, nullptr, nullptr, out, b_proj, B_ * T_, C_, C_);
}

// Round 12
// 236.790 us; speedup vs baseline: 1.0388x; 1.0145x over previous
//
#include <hip/hip_runtime.h>

typedef unsigned short u16;
typedef __attribute__((ext_vector_type(8))) short short8;
typedef __attribute__((ext_vector_type(4))) short short4v;
typedef __attribute__((ext_vector_type(4))) float floatx4;
typedef __attribute__((ext_vector_type(4))) unsigned short ushort4v;

#define B_ 4
#define T_ 2048
#define C_ 1024
#define H_ 16
#define HD_ 64

template <bool V> struct BC { static constexpr bool value = V; };

static __device__ __forceinline__ u16 f2bf(float f) {
  union { float f; unsigned int i; } c; c.f = f;
  unsigned int u = c.i;
  return (u16)((u + 0x7FFFu + ((u >> 16) & 1u)) >> 16);
}
// pack 2 fp32 -> bf16x2 (truncation) in one v_perm_b32
static __device__ __forceinline__ unsigned pk2(float lo, float hi) {
  union { float f; unsigned u; } a, b; a.f = hi; b.f = lo;
  return __builtin_amdgcn_perm(a.u, b.u, 0x07060302u);
}
// pack 2 fp32 -> bf16x2 with round-to-nearest
static __device__ __forceinline__ unsigned pk2r(float lo, float hi) {
  return (unsigned)f2bf(lo) | ((unsigned)f2bf(hi) << 16);
}

// async global->LDS DMA, 16 B/lane; LDS dest = wave-uniform base + lane*16
static __device__ __forceinline__ void gload16(const u16* g, u16* l) {
  __builtin_amdgcn_global_load_lds(
      (const __attribute__((address_space(1))) unsigned int*)(g),
      (__attribute__((address_space(3))) unsigned int*)(l), 16, 0, 0);
}

// ---------------- fused prep: convert x + transpose both weights ----------
__global__ __launch_bounds__(256) void prep_k(const float* __restrict__ x,
                                              const float* __restrict__ w_qkv,
                                              const float* __restrict__ w_proj,
                                              u16* __restrict__ xbf,
                                              u16* __restrict__ wqkvT,
                                              u16* __restrict__ wprojT) {
  const int bid = blockIdx.x;
  if (bid < 8192) {
    const int i = bid * 256 + threadIdx.x;
    const float4 f = ((const float4*)x)[i];
    ushort4v o;
    o.x = f2bf(f.x); o.y = f2bf(f.y); o.z = f2bf(f.z); o.w = f2bf(f.w);
    *(ushort4v*)(xbf + (size_t)i * 4) = o;
    return;
  }
  __shared__ u16 tile[32][33];
  const float* in;
  u16* out;
  int R, Cc, tb;
  if (bid < 11264) {
    in = w_qkv; out = wqkvT; R = C_; Cc = 3 * C_; tb = bid - 8192;
  } else {
    in = w_proj; out = wprojT; R = C_; Cc = C_; tb = bid - 11264;
  }
  const int tpr = Cc / 32;
  const int bx = (tb % tpr) * 32;
  const int by = (tb / tpr) * 32;
  const int tx = threadIdx.x & 31;
  const int ty = threadIdx.x >> 5;
  #pragma unroll
  for (int i = ty; i < 32; i += 8)
    tile[i][tx] = f2bf(in[(size_t)(by + i) * Cc + bx + tx]);
  __syncthreads();
  #pragma unroll
  for (int i = ty; i < 32; i += 8)
    out[(size_t)(bx + i) * R + by + tx] = tile[tx][i];
}

// ---------------- GEMM, B^T operand, BK=64, XCD-swizzled 1D grid ----------
// Tile: 128 x (NT*32). MODE 1 (NT=4): qkv GEMM, Q/K -> natural bf16 rows,
// V tiles -> Vt via in-LDS transpose. MODE 2 (NT=2): fp32 out + bias,
// nontemporal; 1024 blocks = 4 blocks/CU.
template <int MODE, int NT>
__global__ __launch_bounds__(256) void gemm_bt(const u16* __restrict__ A,
                                               const u16* __restrict__ Bt,
                                               u16* __restrict__ outb,
                                               u16* __restrict__ outv,
                                               float* __restrict__ outf,
                                               const float* __restrict__ bias,
                                               int M, int N, int K) {
  __shared__ __align__(16) u16 lds[8192 + NT * 2048];  // A[2][4096] | B[2][NT*1024]
  const int bid = blockIdx.x;
  const int s = bid >> 3;
  const int tM = ((bid & 7) * 8 + (s & 7)) * 128;  // 64 M-tiles = 8 XCD x 8
  const int tN = (s >> 3) * (NT * 32);
  const int tid = threadIdx.x;
  const int wave = tid >> 6;
  const int lane = tid & 63;
  const int lr = lane & 15;
  const int quad = lane >> 4;
  const int wm = (wave >> 1) * 64;
  const int wn = (wave & 1) * (NT * 16);

  const int srow = lane >> 2;
  const int skofs = ((lane & 3) ^ ((lane >> 3) & 3)) * 8;

  const floatx4 zf = {0.f, 0.f, 0.f, 0.f};
  floatx4 acc[4][NT];
  #pragma unroll
  for (int i = 0; i < 4; i++)
    #pragma unroll
    for (int j = 0; j < NT; j++) acc[i][j] = zf;

  const int csw = (lr >> 1) & 3;

  for (int k0 = 0; k0 < K; k0 += 64) {
    __syncthreads();
    #pragma unroll
    for (int half = 0; half < 2; half++) {
      const int kk = k0 + half * 32;
      #pragma unroll
      for (int j = 0; j < 2; j++) {
        const int seg = wave * 2 + j;
        const int row = seg * 16 + srow;
        gload16(A + (size_t)(tM + row) * K + kk + skofs, &lds[half * 4096 + seg * 512]);
      }
      #pragma unroll
      for (int j = 0; j < NT / 2; j++) {
        const int seg = wave * (NT / 2) + j;
        const int row = seg * 16 + srow;
        gload16(Bt + (size_t)(tN + row) * K + kk + skofs,
                &lds[8192 + half * (NT * 1024) + seg * 512]);
      }
    }
    __syncthreads();

    #pragma unroll
    for (int half = 0; half < 2; half++) {
      short8 af[4], bfr[NT];
      #pragma unroll
      for (int mt = 0; mt < 4; mt++)
        af[mt] = *(const short8*)(&lds[half * 4096 + (wm + mt * 16 + lr) * 32 + ((quad ^ csw) * 8)]);
      #pragma unroll
      for (int nt = 0; nt < NT; nt++)
        bfr[nt] = *(const short8*)(&lds[8192 + half * (NT * 1024) + (wn + nt * 16 + lr) * 32 + ((quad ^ csw) * 8)]);
      #pragma unroll
      for (int mt = 0; mt < 4; mt++)
        #pragma unroll
        for (int nt = 0; nt < NT; nt++)
          acc[mt][nt] = __builtin_amdgcn_mfma_f32_16x16x32_bf16(af[mt], bfr[nt],
                                                                acc[mt][nt], 0, 0, 0);
    }
  }

  if (MODE == 1 && tN >= 2 * C_) {
    // V tile: transpose 128x128 through LDS (2 passes of 64 n-rows), write Vt.
    const int b = tM >> 11;
    const int t0 = tM & (T_ - 1);               // within-batch t offset
    const int h0 = (tN - 2 * C_) >> 6;
    #pragma unroll
    for (int pass = 0; pass < 2; pass++) {
      __syncthreads();
      if ((wave & 1) == pass) {
        #pragma unroll
        for (int nt = 0; nt < NT; nt++) {
          const int nr = nt * 16 + lr;
          #pragma unroll
          for (int mt = 0; mt < 4; mt++) {
            const int mr = wm + mt * 16 + quad * 4;
            *(unsigned*)(&lds[nr * 136 + mr]) = pk2r(acc[mt][nt][0], acc[mt][nt][1]);
            *(unsigned*)(&lds[nr * 136 + mr + 2]) = pk2r(acc[mt][nt][2], acc[mt][nt][3]);
          }
        }
      }
      __syncthreads();
      const int bh = b * H_ + h0 + pass;
      u16* vbase = outv + (size_t)bh * HD_ * T_ + t0;
      #pragma unroll
      for (int i = 0; i < 4; i++) {
        const int c = tid + i * 256;
        const int nr = c >> 4, m8 = (c & 15) * 8;
        const short8 v = *(const short8*)(&lds[nr * 136 + m8]);
        *(short8*)(vbase + (size_t)nr * T_ + m8) = v;
      }
    }
    return;
  }

  // natural epilogue: D[row=quad*4+r][col=lane&15]
  #pragma unroll
  for (int mt = 0; mt < 4; mt++) {
    const int m0 = tM + wm + mt * 16 + quad * 4;
    #pragma unroll
    for (int nt = 0; nt < NT; nt++) {
      const int n = tN + wn + nt * 16 + lr;
      #pragma unroll
      for (int r = 0; r < 4; r++) {
        const float v = acc[mt][nt][r];
        const size_t m = (size_t)(m0 + r);
        if (MODE == 2) __builtin_nontemporal_store(v + bias[n], &outf[m * N + n]);
        else           outb[m * N + n] = f2bf(v);
      }
    }
  }
}

// ---------------- causal flash attention: S^T/O^T form, register-P --------
// grid 1024 (XCD-swizzled). kt loop split into 4 constexpr variants:
// both-tiles / diagA / B-only / diagB — no per-iter predicate evaluation.
__global__ __launch_bounds__(256, 4) void attn_k(const u16* __restrict__ qkv,
                                                 const u16* __restrict__ vt,
                                                 u16* __restrict__ y) {
  __shared__ __align__(16) u16 Ks[64 * 64];     // [kpos][d], chunk-swizzled
  __shared__ __align__(16) u16 Vs[64 * 64];     // Vt: [d][kpos], chunk-swizzled
  const int bid = blockIdx.x;
  const int s = bid >> 3;
  const int qp = s >> 3;                     // 0..15
  const int bh = ((s & 7) << 3) | (bid & 7); // all qp of this bh share XCD
  const int b = bh >> 4, h = bh & 15;
  const int tid = threadIdx.x;
  const int wave = tid >> 6;
  const int lane = tid & 63;
  const int lr = lane & 15;
  const int quad = lane >> 4;
  const int qtA = qp, qtB = 31 - qp;         // qtA < qtB always

  const int srow = lane >> 3;
  const int skofs = ((lane & 7) ^ ((lane >> 3) & 7)) * 8;
  const int gsw = lr & 7;

  const size_t RS = 3 * C_;
  const u16* qcol = qkv + (size_t)b * T_ * RS + h * HD_;
  const u16* kcol = qcol + C_;

  const size_t qrA = (size_t)(qtA * 64 + wave * 16 + lr) * RS;
  const size_t qrB = (size_t)(qtB * 64 + wave * 16 + lr) * RS;
  const short8 aq0A = *(const short8*)(qcol + qrA + quad * 8);
  const short8 aq1A = *(const short8*)(qcol + qrA + 32 + quad * 8);
  const short8 aq0B = *(const short8*)(qcol + qrB + quad * 8);
  const short8 aq1B = *(const short8*)(qcol + qrB + 32 + quad * 8);

  const floatx4 zf = {0.f, 0.f, 0.f, 0.f};
  const float C1 = 0.125f * 1.44269504f;
  const float C2 = -16.0f * 1.44269504f;
  const short8 vones = {16256, 16256, 16256, 16256, 16256, 16256, 16256, 16256};

  floatx4 accA[4], accB[4];  // O^T: lane holds O^T[d=dt*16+quad*4+r][q=lr]
  floatx4 accSA = zf, accSB = zf;  // row sums via ones-MFMA
  #pragma unroll
  for (int i = 0; i < 4; i++) { accA[i] = zf; accB[i] = zf; }

  auto stage = [&](int kt) {
    __syncthreads();
    #pragma unroll
    for (int j = 0; j < 2; j++) {
      const int seg = wave * 2 + j;
      const int row = seg * 8 + srow;
      gload16(kcol + (size_t)(kt * 64 + row) * RS + skofs, &Ks[seg * 512]);
      gload16(vt + ((size_t)bh * HD_ + row) * T_ + kt * 64 + skofs, &Vs[seg * 512]);
    }
    __syncthreads();
  };

  auto core = [&](auto WA, auto DA, auto DB) {
    constexpr bool wA = decltype(WA)::value;
    constexpr bool dA = decltype(DA)::value;
    constexpr bool dB = decltype(DB)::value;
    float peA[4][4], peB[4][4];
    #pragma unroll
    for (int nt = 0; nt < 4; nt++) {
      const short8 bk0 =
          *(const short8*)(&Ks[(nt * 16 + lr) * 64 + ((quad ^ gsw) * 8)]);
      const short8 bk1 =
          *(const short8*)(&Ks[(nt * 16 + lr) * 64 + (((quad + 4) ^ gsw) * 8)]);
      {
        floatx4 st = __builtin_amdgcn_mfma_f32_16x16x32_bf16(
            bk1, aq1B,
            __builtin_amdgcn_mfma_f32_16x16x32_bf16(bk0, aq0B, zf, 0, 0, 0),
            0, 0, 0);
        #pragma unroll
        for (int r = 0; r < 4; r++) {
          float pe = __builtin_amdgcn_exp2f(fmaf(st[r], C1, C2));
          if constexpr (dB)
            if (nt * 16 + quad * 4 + r > wave * 16 + lr) pe = 0.f;
          peB[nt][r] = pe;
        }
      }
      if constexpr (wA) {
        floatx4 st = __builtin_amdgcn_mfma_f32_16x16x32_bf16(
            bk1, aq1A,
            __builtin_amdgcn_mfma_f32_16x16x32_bf16(bk0, aq0A, zf, 0, 0, 0),
            0, 0, 0);
        #pragma unroll
        for (int r = 0; r < 4; r++) {
          float pe = __builtin_amdgcn_exp2f(fmaf(st[r], C1, C2));
          if constexpr (dA)
            if (nt * 16 + quad * 4 + r > wave * 16 + lr) pe = 0.f;
          peA[nt][r] = pe;
        }
      }
    }

    short8 pB[2], pA[2];
    #pragma unroll
    for (int h2 = 0; h2 < 2; h2++) {
      union { unsigned u[4]; short8 s8; } w;
      w.u[0] = pk2(peB[2 * h2][0], peB[2 * h2][1]);
      w.u[1] = pk2(peB[2 * h2][2], peB[2 * h2][3]);
      w.u[2] = pk2(peB[2 * h2 + 1][0], peB[2 * h2 + 1][1]);
      w.u[3] = pk2(peB[2 * h2 + 1][2], peB[2 * h2 + 1][3]);
      pB[h2] = w.s8;
    }
    if constexpr (wA) {
      #pragma unroll
      for (int h2 = 0; h2 < 2; h2++) {
        union { unsigned u[4]; short8 s8; } w;
        w.u[0] = pk2(peA[2 * h2][0], peA[2 * h2][1]);
        w.u[1] = pk2(peA[2 * h2][2], peA[2 * h2][3]);
        w.u[2] = pk2(peA[2 * h2 + 1][0], peA[2 * h2 + 1][1]);
        w.u[3] = pk2(peA[2 * h2 + 1][2], peA[2 * h2 + 1][3]);
        pA[h2] = w.s8;
      }
    }

    #pragma unroll
    for (int h2 = 0; h2 < 2; h2++) {
      accSB = __builtin_amdgcn_mfma_f32_16x16x32_bf16(vones, pB[h2], accSB, 0, 0, 0);
      if constexpr (wA)
        accSA = __builtin_amdgcn_mfma_f32_16x16x32_bf16(vones, pA[h2], accSA, 0, 0, 0);
      #pragma unroll
      for (int dt = 0; dt < 4; dt++) {
        const int base = (dt * 16 + lr) * 64;
        const int cl = h2 * 4 + (quad >> 1);
        const int off_lo = ((cl ^ gsw) * 8) + (quad & 1) * 4;
        const int off_hi = (((cl + 2) ^ gsw) * 8) + (quad & 1) * 4;
        const short4v vlo = *(const short4v*)(&Vs[base + off_lo]);
        const short4v vhi = *(const short4v*)(&Vs[base + off_hi]);
        const short8 av = __builtin_shufflevector(vlo, vhi, 0, 1, 2, 3, 4, 5, 6, 7);
        accB[dt] = __builtin_amdgcn_mfma_f32_16x16x32_bf16(av, pB[h2], accB[dt], 0, 0, 0);
        if constexpr (wA)
          accA[dt] = __builtin_amdgcn_mfma_f32_16x16x32_bf16(av, pA[h2], accA[dt], 0, 0, 0);
      }
    }
  };

  for (int kt = 0; kt < qtA; kt++) { stage(kt); core(BC<true>{}, BC<false>{}, BC<false>{}); }
  stage(qtA); core(BC<true>{}, BC<true>{}, BC<false>{});
  for (int kt = qtA + 1; kt < qtB; kt++) { stage(kt); core(BC<false>{}, BC<false>{}, BC<false>{}); }
  stage(qtB); core(BC<false>{}, BC<false>{}, BC<true>{});

  // epilogue: every lane already holds the full row-sum in accS*[0]
  #pragma unroll
  for (int ph = 0; ph < 2; ph++) {
    const int qt = ph ? qtB : qtA;
    const floatx4* acc = ph ? accB : accA;
    const float inv = 1.f / (ph ? accSB[0] : accSA[0]);
    const int qg = qt * 64 + wave * 16 + lr;
    u16* yrow = y + ((size_t)(b * T_ + qg)) * C_ + h * HD_;
    #pragma unroll
    for (int dt = 0; dt < 4; dt++) {
      ushort4v o;
      #pragma unroll
      for (int r = 0; r < 4; r++) o[r] = f2bf(acc[dt][r] * inv);
      *(ushort4v*)(yrow + dt * 16 + quad * 4) = o;
    }
  }
}

extern "C" void kernel_launch(void* const* d_in, const int* in_sizes, int n_in,
                              void* d_out, int out_size, void* d_ws, size_t ws_size,
                              hipStream_t stream) {
  const float* x      = (const float*)d_in[0];  // [B,T,C] fp32
  const float* w_qkv  = (const float*)d_in[1];  // [C,3C]  fp32
  const float* w_proj = (const float*)d_in[2];  // [C,C]   fp32
  const float* b_proj = (const float*)d_in[3];  // [C]     fp32
  float* out = (float*)d_out;                   // [B,T,C] fp32

  u16* ws = (u16*)d_ws;
  const size_t SZ = (size_t)B_ * T_ * C_;          // 8388608
  u16* xbf    = ws;                                // [B,T,C] bf16 (yw aliases later)
  u16* wqkvT  = xbf + SZ;                          // [3C][C]
  u16* wprojT = wqkvT + (size_t)3 * C_ * C_;       // [C][C]
  u16* qkvw   = wprojT + (size_t)C_ * C_;          // [B,T,3C] natural bf16 (V third unused)
  u16* vtw    = qkvw + 3 * SZ;                     // [B,H,HD,T]
  u16* yw     = xbf;                               // x dead after gemm1

  prep_k<<<12288, 256, 0, stream>>>(x, w_qkv, w_proj, xbf, wqkvT, wprojT);
  gemm_bt<1, 4><<<1536, 256, 0, stream>>>(
      xbf, wqkvT, qkvw, vtw, nullptr, nullptr, B_ * T_, 3 * C_, C_);
  attn_k<<<1024, 256, 0, stream>>>(qkvw, vtw, yw);
  gemm_bt<2, 2><<<1024, 256, 0, stream>>>(
      yw, wprojT, nullptr, nullptr, out, b_proj, B_ * T_, C_, C_);
}